// Round 1
// baseline (16670.270 us; speedup 1.0000x reference)
//
#include <hip/hip_runtime.h>
#include <hip/hip_bf16.h>
#include <math.h>

#define TT 2048
#define HID 2560
#define NH 40
#define NOPE 64
#define ROPE 32
#define VDIM 64
#define QLORA 768
#define KVLORA 256
#define DQK 288            // KVLORA + ROPE
#define QHD 96             // NOPE + ROPE
#define EPS 1e-5f
#define THETA 10000.0f

// ---------------- generic tiled fp32 GEMM: C = A(MxK) @ B(KxN) ----------------
__global__ __launch_bounds__(256) void gemm_f32(const float* __restrict__ A,
                                                const float* __restrict__ B,
                                                float* __restrict__ C,
                                                int M, int N, int K) {
    const int BM = 64, BN = 64, BK = 16;
    __shared__ float As[BK][BM + 1];
    __shared__ float Bs[BK][BN + 4];
    int tid = threadIdx.x;
    int block_row = blockIdx.y * BM;
    int block_col = blockIdx.x * BN;
    int ty = tid / 16, tx = tid % 16;
    float acc[4][4] = {};
    int a_r = tid / 4;           // 0..63
    int a_c = (tid % 4) * 4;     // 0,4,8,12
    int b_r = tid / 16;          // 0..15
    int b_c = (tid % 16) * 4;    // 0..60
    for (int k0 = 0; k0 < K; k0 += BK) {
        {
            int gr = block_row + a_r;
            #pragma unroll
            for (int i = 0; i < 4; i++) {
                int gc = k0 + a_c + i;
                float v = (gr < M && gc < K) ? A[(size_t)gr * K + gc] : 0.f;
                As[a_c + i][a_r] = v;
            }
        }
        {
            int gr = k0 + b_r;
            #pragma unroll
            for (int i = 0; i < 4; i++) {
                int gc = block_col + b_c + i;
                float v = (gr < K && gc < N) ? B[(size_t)gr * N + gc] : 0.f;
                Bs[b_r][b_c + i] = v;
            }
        }
        __syncthreads();
        #pragma unroll
        for (int k = 0; k < BK; k++) {
            float ra[4], rb[4];
            #pragma unroll
            for (int i = 0; i < 4; i++) ra[i] = As[k][ty * 4 + i];
            #pragma unroll
            for (int j = 0; j < 4; j++) rb[j] = Bs[k][tx * 4 + j];
            #pragma unroll
            for (int i = 0; i < 4; i++)
                #pragma unroll
                for (int j = 0; j < 4; j++)
                    acc[i][j] += ra[i] * rb[j];
        }
        __syncthreads();
    }
    #pragma unroll
    for (int i = 0; i < 4; i++) {
        int gr = block_row + ty * 4 + i;
        if (gr >= M) continue;
        #pragma unroll
        for (int j = 0; j < 4; j++) {
            int gc = block_col + tx * 4 + j;
            if (gc < N) C[(size_t)gr * N + gc] = acc[i][j];
        }
    }
}

// ---------------- RMS norm in place over QLORA per row ----------------
__global__ __launch_bounds__(256) void rms_qa(float* __restrict__ x, const float* __restrict__ g) {
    int t = blockIdx.x, tid = threadIdx.x;
    __shared__ float red[256];
    __shared__ float s_inv;
    float* row = x + (size_t)t * QLORA;
    float ss = 0.f;
    for (int i = tid; i < QLORA; i += 256) { float v = row[i]; ss += v * v; }
    red[tid] = ss; __syncthreads();
    for (int s = 128; s > 0; s >>= 1) { if (tid < s) red[tid] += red[tid + s]; __syncthreads(); }
    if (tid == 0) s_inv = rsqrtf(red[0] / (float)QLORA + EPS);
    __syncthreads();
    float si = s_inv;
    for (int i = tid; i < QLORA; i += 256) row[i] *= si * g[i];
}

// ---------------- latent post: RMS first 256, RoPE last 32 (in place) ----------------
__global__ __launch_bounds__(256) void kin_post(float* __restrict__ kin, const float* __restrict__ g,
                                                const int* __restrict__ positions) {
    int t = blockIdx.x, tid = threadIdx.x;
    __shared__ float red[256];
    __shared__ float s_inv;
    float* row = kin + (size_t)t * DQK;
    float v = row[tid];
    red[tid] = v * v; __syncthreads();
    for (int s = 128; s > 0; s >>= 1) { if (tid < s) red[tid] += red[tid + s]; __syncthreads(); }
    if (tid == 0) s_inv = rsqrtf(red[0] / (float)KVLORA + EPS);
    __syncthreads();
    row[tid] = v * s_inv * g[tid];
    if (tid < 16) {
        float pos = (float)positions[t];
        float freq = powf(THETA, -(float)tid / 16.0f);
        float f = pos * freq;
        float c = cosf(f), s = sinf(f);
        float x1 = row[KVLORA + tid], x2 = row[KVLORA + 16 + tid];
        row[KVLORA + tid]      = x1 * c - x2 * s;
        row[KVLORA + 16 + tid] = x2 * c + x1 * s;
    }
}

// ---------------- q_in build: q_lat = q_nope @ w_kc[h], + RoPE(q_pe) ----------------
__global__ __launch_bounds__(256) void build_qin(const float* __restrict__ q,
                                                 const float* __restrict__ w_kc,
                                                 const int* __restrict__ positions,
                                                 float* __restrict__ qin) {
    int t = blockIdx.x, h = blockIdx.y, tid = threadIdx.x;
    __shared__ float qn[NOPE];
    const float* qrow = q + (size_t)t * (NH * QHD) + h * QHD;
    if (tid < NOPE) qn[tid] = qrow[tid];
    __syncthreads();
    const float* w = w_kc + (size_t)h * NOPE * KVLORA + tid;  // stride KVLORA over n
    float acc = 0.f;
    #pragma unroll 8
    for (int n = 0; n < NOPE; n++) acc += qn[n] * w[(size_t)n * KVLORA];
    float* orow = qin + ((size_t)t * NH + h) * DQK;
    orow[tid] = acc;
    if (tid < 16) {
        float pos = (float)positions[t];
        float freq = powf(THETA, -(float)tid / 16.0f);
        float f = pos * freq;
        float c = cosf(f), s = sinf(f);
        float x1 = qrow[NOPE + tid], x2 = qrow[NOPE + 16 + tid];
        orow[KVLORA + tid]      = x1 * c - x2 * s;
        orow[KVLORA + 16 + tid] = x2 * c + x1 * s;
    }
}

// ---------------- attention: one block per (t, h) ----------------
__global__ __launch_bounds__(256) void attn(const float* __restrict__ qin,
                                            const float* __restrict__ kin,
                                            float* __restrict__ o_lat) {
    int t = blockIdx.x, h = blockIdx.y, tid = threadIdx.x;
    __shared__ float qs[DQK];
    __shared__ float sc[TT];
    __shared__ float red[256];
    const float* qrow = qin + ((size_t)t * NH + h) * DQK;
    for (int i = tid; i < DQK; i += 256) qs[i] = qrow[i];
    __syncthreads();
    const float scale = 1.0f / sqrtf((float)QHD);
    float lmax = -1e30f;
    for (int s = tid; s <= t; s += 256) {
        const float* krow = kin + (size_t)s * DQK;
        float d = 0.f;
        #pragma unroll 8
        for (int i = 0; i < DQK; i++) d += qs[i] * krow[i];
        d *= scale;
        sc[s] = d;
        if (d > lmax) lmax = d;
    }
    red[tid] = lmax; __syncthreads();
    for (int s2 = 128; s2 > 0; s2 >>= 1) { if (tid < s2) red[tid] = fmaxf(red[tid], red[tid + s2]); __syncthreads(); }
    float m = red[0]; __syncthreads();
    float lsum = 0.f;
    for (int s = tid; s <= t; s += 256) {
        float p = expf(sc[s] - m);
        sc[s] = p;
        lsum += p;
    }
    red[tid] = lsum; __syncthreads();
    for (int s2 = 128; s2 > 0; s2 >>= 1) { if (tid < s2) red[tid] += red[tid + s2]; __syncthreads(); }
    float inv_l = 1.0f / red[0];
    __syncthreads();
    // o_lat[k] = sum_s p[s] * v_in[s,k]; v_in is kin[:, 0:256]
    float acc = 0.f;
    for (int s = 0; s <= t; s++) acc += sc[s] * kin[(size_t)s * DQK + tid];
    o_lat[((size_t)t * NH + h) * KVLORA + tid] = acc * inv_l;
}

// ---------------- o = o_lat @ w_vc[h] ----------------
__global__ __launch_bounds__(64) void ogemm(const float* __restrict__ o_lat,
                                            const float* __restrict__ w_vc,
                                            float* __restrict__ o) {
    int t = blockIdx.x, h = blockIdx.y, tid = threadIdx.x;  // 64 threads
    __shared__ float ol[KVLORA];
    const float* row = o_lat + ((size_t)t * NH + h) * KVLORA;
    for (int i = tid; i < KVLORA; i += 64) ol[i] = row[i];
    __syncthreads();
    const float* w = w_vc + (size_t)h * KVLORA * VDIM + tid;  // stride VDIM over k
    float acc = 0.f;
    #pragma unroll 8
    for (int k = 0; k < KVLORA; k++) acc += ol[k] * w[(size_t)k * VDIM];
    o[(size_t)t * HID + h * VDIM + tid] = acc;
}

extern "C" void kernel_launch(void* const* d_in, const int* in_sizes, int n_in,
                              void* d_out, int out_size, void* d_ws, size_t ws_size,
                              hipStream_t stream) {
    const int*   positions = (const int*)d_in[0];
    const float* hs    = (const float*)d_in[1];
    const float* w_qa  = (const float*)d_in[2];
    const float* g_qa  = (const float*)d_in[3];
    const float* w_qb  = (const float*)d_in[4];
    const float* w_kva = (const float*)d_in[5];
    const float* g_kva = (const float*)d_in[6];
    const float* w_kc  = (const float*)d_in[7];
    const float* w_vc  = (const float*)d_in[8];
    const float* w_o   = (const float*)d_in[9];
    float* out = (float*)d_out;

    float* ws    = (float*)d_ws;
    float* qa    = ws;                               // T*QLORA
    float* q     = qa    + (size_t)TT * QLORA;       // T*H*96
    float* kin   = q     + (size_t)TT * NH * QHD;    // T*288
    float* qin   = kin   + (size_t)TT * DQK;         // T*H*288
    float* o_lat = qin   + (size_t)TT * NH * DQK;    // T*H*256
    float* o     = o_lat + (size_t)TT * NH * KVLORA; // T*2560

    dim3 blk(256);

    // 1. qa = hs @ w_qa; RMS
    gemm_f32<<<dim3(QLORA / 64, TT / 64), blk, 0, stream>>>(hs, w_qa, qa, TT, QLORA, HID);
    rms_qa<<<TT, 256, 0, stream>>>(qa, g_qa);
    // 2. q = qa @ w_qb
    gemm_f32<<<dim3((NH * QHD) / 64, TT / 64), blk, 0, stream>>>(qa, w_qb, q, TT, NH * QHD, QLORA);
    // 3. kin = hs @ w_kva; RMS(first 256) + RoPE(last 32)
    gemm_f32<<<dim3((DQK + 63) / 64, TT / 64), blk, 0, stream>>>(hs, w_kva, kin, TT, DQK, HID);
    kin_post<<<TT, 256, 0, stream>>>(kin, g_kva, positions);
    // 4. qin = [q_nope @ w_kc[h] | rope(q_pe)]
    build_qin<<<dim3(TT, NH), 256, 0, stream>>>(q, w_kc, positions, qin);
    // 5. attention
    attn<<<dim3(TT, NH), 256, 0, stream>>>(qin, kin, o_lat);
    // 6. o = o_lat @ w_vc
    ogemm<<<dim3(TT, NH), 64, 0, stream>>>(o_lat, w_vc, o);
    // 7. out = o @ w_o
    gemm_f32<<<dim3(HID / 64, TT / 64), blk, 0, stream>>>(o, w_o, out, TT, HID, HID);
}

// Round 2
// 2498.119 us; speedup vs baseline: 6.6731x; 6.6731x over previous
//
#include <hip/hip_runtime.h>
#include <hip/hip_bf16.h>
#include <math.h>

#define TT 2048
#define HID 2560
#define NH 40
#define NOPE 64
#define ROPE 32
#define VDIM 64
#define QLORA 768
#define KVLORA 256
#define DQK 288            // KVLORA + ROPE
#define QHD 96             // NOPE + ROPE
#define EPS 1e-5f
#define THETA 10000.0f

typedef __attribute__((ext_vector_type(8))) short bf16x8;
typedef __attribute__((ext_vector_type(4))) float f32x4;

static __device__ __forceinline__ ushort f2bf(float x) {
    __hip_bfloat16 b = __float2bfloat16(x);
    return *reinterpret_cast<ushort*>(&b);
}

// ---------------- generic tiled fp32 GEMM: C = A(MxK) @ B(KxN) ----------------
__global__ __launch_bounds__(256) void gemm_f32(const float* __restrict__ A,
                                                const float* __restrict__ B,
                                                float* __restrict__ C,
                                                int M, int N, int K) {
    const int BM = 64, BN = 64, BK = 16;
    __shared__ float As[BK][BM + 1];
    __shared__ float Bs[BK][BN + 4];
    int tid = threadIdx.x;
    int block_row = blockIdx.y * BM;
    int block_col = blockIdx.x * BN;
    int ty = tid / 16, tx = tid % 16;
    float acc[4][4] = {};
    int a_r = tid / 4;
    int a_c = (tid % 4) * 4;
    int b_r = tid / 16;
    int b_c = (tid % 16) * 4;
    for (int k0 = 0; k0 < K; k0 += BK) {
        {
            int gr = block_row + a_r;
            #pragma unroll
            for (int i = 0; i < 4; i++) {
                int gc = k0 + a_c + i;
                float v = (gr < M && gc < K) ? A[(size_t)gr * K + gc] : 0.f;
                As[a_c + i][a_r] = v;
            }
        }
        {
            int gr = k0 + b_r;
            #pragma unroll
            for (int i = 0; i < 4; i++) {
                int gc = block_col + b_c + i;
                float v = (gr < K && gc < N) ? B[(size_t)gr * N + gc] : 0.f;
                Bs[b_r][b_c + i] = v;
            }
        }
        __syncthreads();
        #pragma unroll
        for (int k = 0; k < BK; k++) {
            float ra[4], rb[4];
            #pragma unroll
            for (int i = 0; i < 4; i++) ra[i] = As[k][ty * 4 + i];
            #pragma unroll
            for (int j = 0; j < 4; j++) rb[j] = Bs[k][tx * 4 + j];
            #pragma unroll
            for (int i = 0; i < 4; i++)
                #pragma unroll
                for (int j = 0; j < 4; j++)
                    acc[i][j] += ra[i] * rb[j];
        }
        __syncthreads();
    }
    #pragma unroll
    for (int i = 0; i < 4; i++) {
        int gr = block_row + ty * 4 + i;
        if (gr >= M) continue;
        #pragma unroll
        for (int j = 0; j < 4; j++) {
            int gc = block_col + tx * 4 + j;
            if (gc < N) C[(size_t)gr * N + gc] = acc[i][j];
        }
    }
}

// ---------------- RMS norm in place over QLORA per row ----------------
__global__ __launch_bounds__(256) void rms_qa(float* __restrict__ x, const float* __restrict__ g) {
    int t = blockIdx.x, tid = threadIdx.x;
    __shared__ float red[256];
    __shared__ float s_inv;
    float* row = x + (size_t)t * QLORA;
    float ss = 0.f;
    for (int i = tid; i < QLORA; i += 256) { float v = row[i]; ss += v * v; }
    red[tid] = ss; __syncthreads();
    for (int s = 128; s > 0; s >>= 1) { if (tid < s) red[tid] += red[tid + s]; __syncthreads(); }
    if (tid == 0) s_inv = rsqrtf(red[0] / (float)QLORA + EPS);
    __syncthreads();
    float si = s_inv;
    for (int i = tid; i < QLORA; i += 256) row[i] *= si * g[i];
}

// ------- latent post: RMS first 256, RoPE last 32 → bf16 kin_bf (T x 288) -------
__global__ __launch_bounds__(256) void kin_post(const float* __restrict__ kin,
                                                const float* __restrict__ g,
                                                const int* __restrict__ positions,
                                                ushort* __restrict__ kin_bf) {
    int t = blockIdx.x, tid = threadIdx.x;
    __shared__ float red[256];
    __shared__ float s_inv;
    const float* row = kin + (size_t)t * DQK;
    float v = row[tid];
    red[tid] = v * v; __syncthreads();
    for (int s = 128; s > 0; s >>= 1) { if (tid < s) red[tid] += red[tid + s]; __syncthreads(); }
    if (tid == 0) s_inv = rsqrtf(red[0] / (float)KVLORA + EPS);
    __syncthreads();
    ushort* orow = kin_bf + (size_t)t * DQK;
    orow[tid] = f2bf(v * s_inv * g[tid]);
    if (tid < 16) {
        float pos = (float)positions[t];
        float freq = powf(THETA, -(float)tid / 16.0f);
        float f = pos * freq;
        float c = cosf(f), s = sinf(f);
        float x1 = row[KVLORA + tid], x2 = row[KVLORA + 16 + tid];
        orow[KVLORA + tid]      = f2bf(x1 * c - x2 * s);
        orow[KVLORA + 16 + tid] = f2bf(x2 * c + x1 * s);
    }
}

// --- q_in build: q_lat = q_nope @ w_kc[h] + RoPE(q_pe), scaled, → bf16 (T,NH,288) ---
__global__ __launch_bounds__(256) void build_qin(const float* __restrict__ q,
                                                 const float* __restrict__ w_kc,
                                                 const int* __restrict__ positions,
                                                 ushort* __restrict__ qin) {
    int t = blockIdx.x, h = blockIdx.y, tid = threadIdx.x;
    const float scale = 0.10206207261596577f;   // 1/sqrt(96), folded into Q
    __shared__ float qn[NOPE];
    const float* qrow = q + (size_t)t * (NH * QHD) + h * QHD;
    if (tid < NOPE) qn[tid] = qrow[tid];
    __syncthreads();
    const float* w = w_kc + (size_t)h * NOPE * KVLORA + tid;
    float acc = 0.f;
    #pragma unroll 8
    for (int n = 0; n < NOPE; n++) acc += qn[n] * w[(size_t)n * KVLORA];
    ushort* orow = qin + ((size_t)t * NH + h) * DQK;
    orow[tid] = f2bf(acc * scale);
    if (tid < 16) {
        float pos = (float)positions[t];
        float freq = powf(THETA, -(float)tid / 16.0f);
        float f = pos * freq;
        float c = cosf(f), s = sinf(f);
        float x1 = qrow[NOPE + tid], x2 = qrow[NOPE + 16 + tid];
        orow[KVLORA + tid]      = f2bf((x1 * c - x2 * s) * scale);
        orow[KVLORA + 16 + tid] = f2bf((x2 * c + x1 * s) * scale);
    }
}

// ---------------- flash MFMA attention ----------------
// block = (q-tile of 64 rows, head). 4 waves, wave w owns rows 16w..16w+15.
// LDS: krow  64 x 296 (row-major K tile, bf16)     -- B-operand for QK^T
//      vt   256 x  72 (transposed V tile, padded)  -- B-operand for PV
//      pbuf 64 x 72 ALIASES krow (krow reloaded every tile; P written between barriers)
#define KSTR 296
#define VSTR 72
#define PSTR 72

__global__ __launch_bounds__(256, 2) void flash_attn(const ushort* __restrict__ qin,
                                                     const ushort* __restrict__ kin,
                                                     float* __restrict__ o_lat) {
    __shared__ ushort lds[64 * KSTR + 256 * VSTR];
    ushort* krow = lds;
    ushort* vt   = lds + 64 * KSTR;
    ushort* pbuf = lds;                 // alias of krow region

    const int tid  = threadIdx.x;
    const int lane = tid & 63;
    const int wv   = tid >> 6;          // wave 0..3
    const int col  = lane & 15;
    const int quad = lane >> 4;
    const int h    = blockIdx.y;
    const int qb   = ((int)gridDim.x - 1 - (int)blockIdx.x) * 64;  // heavy tiles first

    // Q A-fragments: rows qb+wv*16+col, 9 k-chunks of 32
    bf16x8 qf[9];
    {
        const ushort* base = qin + ((size_t)(qb + wv * 16 + col) * NH + h) * DQK + quad * 8;
        #pragma unroll
        for (int k = 0; k < 9; k++) qf[k] = *(const bf16x8*)(base + k * 32);
    }

    f32x4 of[16];
    #pragma unroll
    for (int i = 0; i < 16; i++) of[i] = (f32x4){0.f, 0.f, 0.f, 0.f};
    float m_i[4] = {-1e30f, -1e30f, -1e30f, -1e30f};
    float l_i[4] = {0.f, 0.f, 0.f, 0.f};

    for (int s0 = 0; s0 <= qb; s0 += 64) {
        __syncthreads();   // prev PV reads (pbuf/vt) done before staging overwrites
        // ---- stage K tile: global bf16 -> krow (row-major) + vt (transposed) ----
        {
            const ushort* src = kin + (size_t)(s0 + lane) * DQK;
            #pragma unroll
            for (int ci = 0; ci < 9; ci++) {
                int c = ci * 4 + wv;            // 0..35
                uint4 u = *(const uint4*)(src + c * 8);
                *(uint4*)(krow + lane * KSTR + c * 8) = u;
                if (c < 32) {
                    const ushort* up = (const ushort*)&u;
                    #pragma unroll
                    for (int j = 0; j < 8; j++)
                        vt[(c * 8 + j) * VSTR + lane] = up[j];
                }
            }
        }
        __syncthreads();
        // ---- S = Q K^T  (4 col-tiles x 9 k-steps) ----
        f32x4 sf[4];
        #pragma unroll
        for (int tc = 0; tc < 4; tc++) sf[tc] = (f32x4){0.f, 0.f, 0.f, 0.f};
        #pragma unroll
        for (int k = 0; k < 9; k++) {
            #pragma unroll
            for (int tc = 0; tc < 4; tc++) {
                bf16x8 bf = *(const bf16x8*)(krow + (tc * 16 + col) * KSTR + k * 32 + quad * 8);
                sf[tc] = __builtin_amdgcn_mfma_f32_16x16x32_bf16(qf[k], bf, sf[tc], 0, 0, 0);
            }
        }
        // ---- causal mask (only diagonal tile) ----
        if (s0 == qb) {
            #pragma unroll
            for (int tc = 0; tc < 4; tc++)
                #pragma unroll
                for (int r = 0; r < 4; r++)
                    if (tc * 16 + col > wv * 16 + quad * 4 + r) sf[tc][r] = -1e30f;
        }
        // ---- online softmax (C layout: row = quad*4+reg, col = lane&15) ----
        float mnew[4], alpha[4];
        #pragma unroll
        for (int r = 0; r < 4; r++) {
            float mx = fmaxf(fmaxf(sf[0][r], sf[1][r]), fmaxf(sf[2][r], sf[3][r]));
            mx = fmaxf(mx, __shfl_xor(mx, 1));
            mx = fmaxf(mx, __shfl_xor(mx, 2));
            mx = fmaxf(mx, __shfl_xor(mx, 4));
            mx = fmaxf(mx, __shfl_xor(mx, 8));
            mnew[r] = fmaxf(m_i[r], mx);
            alpha[r] = __expf(m_i[r] - mnew[r]);
            m_i[r] = mnew[r];
        }
        float rsum[4];
        #pragma unroll
        for (int r = 0; r < 4; r++) {
            float s = 0.f;
            #pragma unroll
            for (int tc = 0; tc < 4; tc++) {
                float p = __expf(sf[tc][r] - mnew[r]);
                sf[tc][r] = p;
                s += p;
            }
            s += __shfl_xor(s, 1);
            s += __shfl_xor(s, 2);
            s += __shfl_xor(s, 4);
            s += __shfl_xor(s, 8);
            rsum[r] = s;
        }
        #pragma unroll
        for (int r = 0; r < 4; r++) l_i[r] = l_i[r] * alpha[r] + rsum[r];
        #pragma unroll
        for (int i = 0; i < 16; i++)
            #pragma unroll
            for (int r = 0; r < 4; r++) of[i][r] *= alpha[r];
        __syncthreads();   // all waves done reading krow before P overwrites it
        // ---- P: C-layout regs -> LDS -> A-layout frags ----
        #pragma unroll
        for (int tc = 0; tc < 4; tc++)
            #pragma unroll
            for (int r = 0; r < 4; r++)
                pbuf[(wv * 16 + quad * 4 + r) * PSTR + tc * 16 + col] = f2bf(sf[tc][r]);
        __syncthreads();
        bf16x8 pa[2];
        #pragma unroll
        for (int ks = 0; ks < 2; ks++)
            pa[ks] = *(const bf16x8*)(pbuf + (wv * 16 + col) * PSTR + ks * 32 + quad * 8);
        // ---- O += P V  (16 n-tiles x 2 k-steps) ----
        #pragma unroll
        for (int nt = 0; nt < 16; nt++) {
            #pragma unroll
            for (int ks = 0; ks < 2; ks++) {
                bf16x8 vb = *(const bf16x8*)(vt + (nt * 16 + col) * VSTR + ks * 32 + quad * 8);
                of[nt] = __builtin_amdgcn_mfma_f32_16x16x32_bf16(pa[ks], vb, of[nt], 0, 0, 0);
            }
        }
    }
    // ---- epilogue: divide by l, store o_lat fp32 ----
    #pragma unroll
    for (int r = 0; r < 4; r++) {
        float inv = 1.0f / l_i[r];
        int row = qb + wv * 16 + quad * 4 + r;
        float* dst = o_lat + ((size_t)row * NH + h) * KVLORA + col;
        #pragma unroll
        for (int nt = 0; nt < 16; nt++) dst[nt * 16] = of[nt][r] * inv;
    }
}

// ---------------- o = o_lat @ w_vc[h] ----------------
__global__ __launch_bounds__(64) void ogemm(const float* __restrict__ o_lat,
                                            const float* __restrict__ w_vc,
                                            float* __restrict__ o) {
    int t = blockIdx.x, h = blockIdx.y, tid = threadIdx.x;
    __shared__ float ol[KVLORA];
    const float* row = o_lat + ((size_t)t * NH + h) * KVLORA;
    for (int i = tid; i < KVLORA; i += 64) ol[i] = row[i];
    __syncthreads();
    const float* w = w_vc + (size_t)h * KVLORA * VDIM + tid;
    float acc = 0.f;
    #pragma unroll 8
    for (int k = 0; k < KVLORA; k++) acc += ol[k] * w[(size_t)k * VDIM];
    o[(size_t)t * HID + h * VDIM + tid] = acc;
}

extern "C" void kernel_launch(void* const* d_in, const int* in_sizes, int n_in,
                              void* d_out, int out_size, void* d_ws, size_t ws_size,
                              hipStream_t stream) {
    const int*   positions = (const int*)d_in[0];
    const float* hs    = (const float*)d_in[1];
    const float* w_qa  = (const float*)d_in[2];
    const float* g_qa  = (const float*)d_in[3];
    const float* w_qb  = (const float*)d_in[4];
    const float* w_kva = (const float*)d_in[5];
    const float* g_kva = (const float*)d_in[6];
    const float* w_kc  = (const float*)d_in[7];
    const float* w_vc  = (const float*)d_in[8];
    const float* w_o   = (const float*)d_in[9];
    float* out = (float*)d_out;

    float* ws    = (float*)d_ws;
    float* qa    = ws;                               // T*QLORA
    float* q     = qa    + (size_t)TT * QLORA;       // T*H*96
    float* kin   = q     + (size_t)TT * NH * QHD;    // T*288
    float* o_lat = kin   + (size_t)TT * DQK;         // T*H*256
    float* o     = o_lat + (size_t)TT * NH * KVLORA; // T*2560
    ushort* kin_bf = (ushort*)(o + (size_t)TT * HID);        // T*288 bf16
    ushort* qin_bf = kin_bf + (size_t)TT * DQK;              // T*H*288 bf16

    dim3 blk(256);

    // 1. qa = hs @ w_qa; RMS
    gemm_f32<<<dim3(QLORA / 64, TT / 64), blk, 0, stream>>>(hs, w_qa, qa, TT, QLORA, HID);
    rms_qa<<<TT, 256, 0, stream>>>(qa, g_qa);
    // 2. q = qa @ w_qb
    gemm_f32<<<dim3((NH * QHD) / 64, TT / 64), blk, 0, stream>>>(qa, w_qb, q, TT, NH * QHD, QLORA);
    // 3. kin = hs @ w_kva; RMS(first 256) + RoPE(last 32) -> bf16
    gemm_f32<<<dim3((DQK + 63) / 64, TT / 64), blk, 0, stream>>>(hs, w_kva, kin, TT, DQK, HID);
    kin_post<<<TT, 256, 0, stream>>>(kin, g_kva, positions, kin_bf);
    // 4. qin_bf = [q_nope @ w_kc[h] | rope(q_pe)] * scale, bf16
    build_qin<<<dim3(TT, NH), 256, 0, stream>>>(q, w_kc, positions, qin_bf);
    // 5. flash MFMA attention
    flash_attn<<<dim3(TT / 64, NH), 256, 0, stream>>>(qin_bf, kin_bf, o_lat);
    // 6. o = o_lat @ w_vc
    ogemm<<<dim3(TT, NH), 64, 0, stream>>>(o_lat, w_vc, o);
    // 7. out = o @ w_o
    gemm_f32<<<dim3(HID / 64, TT / 64), blk, 0, stream>>>(o, w_o, out, TT, HID, HID);
}

// Round 3
// 1130.549 us; speedup vs baseline: 14.7453x; 2.2097x over previous
//
#include <hip/hip_runtime.h>
#include <hip/hip_bf16.h>
#include <math.h>

#define TT 2048
#define HID 2560
#define NH 40
#define NOPE 64
#define ROPE 32
#define VDIM 64
#define QLORA 768
#define KVLORA 256
#define DQK 288            // KVLORA + ROPE
#define QHD 96             // NOPE + ROPE
#define EPS 1e-5f
#define THETA 10000.0f

typedef __attribute__((ext_vector_type(8))) short bf16x8;
typedef __attribute__((ext_vector_type(4))) float f32x4;
typedef __attribute__((address_space(1))) const void* gas_t;
typedef __attribute__((address_space(3))) void* las_t;

static __device__ __forceinline__ ushort f2bf(float x) {
    __hip_bfloat16 b = __float2bfloat16(x);
    return *reinterpret_cast<ushort*>(&b);
}

// ---------------- flat fp32 -> bf16 cast ----------------
__global__ __launch_bounds__(256) void cast_bf16(const float* __restrict__ x,
                                                 ushort* __restrict__ y, int n) {
    int i = (blockIdx.x * 256 + threadIdx.x) * 4;
    if (i + 3 < n) {
        float4 v = *(const float4*)(x + i);
        y[i]     = f2bf(v.x);
        y[i + 1] = f2bf(v.y);
        y[i + 2] = f2bf(v.z);
        y[i + 3] = f2bf(v.w);
    }
}

// ------------- transpose + cast: w (K x N fp32) -> wt (N x K bf16) -------------
__global__ __launch_bounds__(256) void transpose_cast(const float* __restrict__ w,
                                                      ushort* __restrict__ wt,
                                                      int K, int N) {
    __shared__ float tile[32][33];
    int bn = blockIdx.x * 32, bk = blockIdx.y * 32;
    int tx = threadIdx.x % 32, ty = threadIdx.x / 32;   // 32 x 8
    #pragma unroll
    for (int i = 0; i < 32; i += 8) {
        int k = bk + ty + i, n = bn + tx;
        if (k < K && n < N) tile[ty + i][tx] = w[(size_t)k * N + n];
    }
    __syncthreads();
    #pragma unroll
    for (int i = 0; i < 32; i += 8) {
        int n = bn + ty + i, k = bk + tx;
        if (n < N && k < K) wt[(size_t)n * K + k] = f2bf(tile[tx][ty + i]);
    }
}

// ------- bf16 MFMA GEMM (m97 structure): C(MxN,f32) = A(MxK,bf16) @ Bt(NxK,bf16)^T -------
// 128x128 tile, BK=32, global_load_lds width=16, 4 waves each owning a 64x64 quadrant.
__global__ __launch_bounds__(256, 2) void gemm_bf16(const ushort* __restrict__ A,
                                                    const ushort* __restrict__ Bt,
                                                    float* __restrict__ C,
                                                    int M, int N, int K) {
    __shared__ ushort As[128 * 32];
    __shared__ ushort Bs[128 * 32];
    const int tid  = threadIdx.x;
    const int lane = tid & 63;
    const int wv   = tid >> 6;
    const int col  = lane & 15;
    const int quad = lane >> 4;
    const int m0 = blockIdx.y * 128, n0 = blockIdx.x * 128;
    const int wr = (wv >> 1) * 64, wc = (wv & 1) * 64;

    f32x4 acc[4][4];
    #pragma unroll
    for (int i = 0; i < 4; i++)
        #pragma unroll
        for (int j = 0; j < 4; j++) acc[i][j] = (f32x4){0.f, 0.f, 0.f, 0.f};

    for (int k0 = 0; k0 < K; k0 += 32) {
        // ---- stage A,Bt tiles: 512 x 16B slots each, 2 per thread per matrix ----
        #pragma unroll
        for (int j = 0; j < 2; j++) {
            int slot = wv * 128 + j * 64 + lane;     // 0..511
            int row  = slot >> 2;
            int ch   = slot & 3;
            const ushort* ga = A + (size_t)(m0 + row) * K + k0 + ch * 8;
            __builtin_amdgcn_global_load_lds((gas_t)ga, (las_t)(As + slot * 8), 16, 0, 0);
            int brow = n0 + row; if (brow >= N) brow = N - 1;   // clamp (edge tiles)
            const ushort* gb = Bt + (size_t)brow * K + k0 + ch * 8;
            __builtin_amdgcn_global_load_lds((gas_t)gb, (las_t)(Bs + slot * 8), 16, 0, 0);
        }
        __syncthreads();
        bf16x8 af[4], bfr[4];
        #pragma unroll
        for (int i = 0; i < 4; i++)
            af[i] = *(const bf16x8*)(As + (wr + i * 16 + col) * 32 + quad * 8);
        #pragma unroll
        for (int j = 0; j < 4; j++)
            bfr[j] = *(const bf16x8*)(Bs + (wc + j * 16 + col) * 32 + quad * 8);
        #pragma unroll
        for (int i = 0; i < 4; i++)
            #pragma unroll
            for (int j = 0; j < 4; j++)
                acc[i][j] = __builtin_amdgcn_mfma_f32_16x16x32_bf16(af[i], bfr[j], acc[i][j], 0, 0, 0);
        __syncthreads();
    }
    #pragma unroll
    for (int i = 0; i < 4; i++) {
        int gr = m0 + wr + i * 16 + quad * 4;
        #pragma unroll
        for (int j = 0; j < 4; j++) {
            int gc = n0 + wc + j * 16 + col;
            if (gc < N) {
                #pragma unroll
                for (int r = 0; r < 4; r++)
                    C[(size_t)(gr + r) * N + gc] = acc[i][j][r];
            }
        }
    }
}

// ---------------- RMS norm: fp32 in, bf16 out ----------------
__global__ __launch_bounds__(256) void rms_qa(const float* __restrict__ x,
                                              const float* __restrict__ g,
                                              ushort* __restrict__ y) {
    int t = blockIdx.x, tid = threadIdx.x;
    __shared__ float red[256];
    __shared__ float s_inv;
    const float* row = x + (size_t)t * QLORA;
    float ss = 0.f;
    for (int i = tid; i < QLORA; i += 256) { float v = row[i]; ss += v * v; }
    red[tid] = ss; __syncthreads();
    for (int s = 128; s > 0; s >>= 1) { if (tid < s) red[tid] += red[tid + s]; __syncthreads(); }
    if (tid == 0) s_inv = rsqrtf(red[0] / (float)QLORA + EPS);
    __syncthreads();
    float si = s_inv;
    ushort* orow = y + (size_t)t * QLORA;
    for (int i = tid; i < QLORA; i += 256) orow[i] = f2bf(row[i] * si * g[i]);
}

// ------- latent post: RMS first 256, RoPE last 32 -> bf16 kin_bf (T x 288) -------
__global__ __launch_bounds__(256) void kin_post(const float* __restrict__ kin,
                                                const float* __restrict__ g,
                                                const int* __restrict__ positions,
                                                ushort* __restrict__ kin_bf) {
    int t = blockIdx.x, tid = threadIdx.x;
    __shared__ float red[256];
    __shared__ float s_inv;
    const float* row = kin + (size_t)t * DQK;
    float v = row[tid];
    red[tid] = v * v; __syncthreads();
    for (int s = 128; s > 0; s >>= 1) { if (tid < s) red[tid] += red[tid + s]; __syncthreads(); }
    if (tid == 0) s_inv = rsqrtf(red[0] / (float)KVLORA + EPS);
    __syncthreads();
    ushort* orow = kin_bf + (size_t)t * DQK;
    orow[tid] = f2bf(v * s_inv * g[tid]);
    if (tid < 16) {
        float pos = (float)positions[t];
        float freq = powf(THETA, -(float)tid / 16.0f);
        float f = pos * freq;
        float c = cosf(f), s = sinf(f);
        float x1 = row[KVLORA + tid], x2 = row[KVLORA + 16 + tid];
        orow[KVLORA + tid]      = f2bf(x1 * c - x2 * s);
        orow[KVLORA + 16 + tid] = f2bf(x2 * c + x1 * s);
    }
}

// --- q_in build: q_lat = q_nope @ w_kc[h] + RoPE(q_pe), scaled, -> bf16 (T,NH,288) ---
__global__ __launch_bounds__(256) void build_qin(const float* __restrict__ q,
                                                 const float* __restrict__ w_kc,
                                                 const int* __restrict__ positions,
                                                 ushort* __restrict__ qin) {
    int t = blockIdx.x, h = blockIdx.y, tid = threadIdx.x;
    const float scale = 0.10206207261596577f;   // 1/sqrt(96), folded into Q
    __shared__ float qn[NOPE];
    const float* qrow = q + (size_t)t * (NH * QHD) + h * QHD;
    if (tid < NOPE) qn[tid] = qrow[tid];
    __syncthreads();
    const float* w = w_kc + (size_t)h * NOPE * KVLORA + tid;
    float acc = 0.f;
    #pragma unroll 8
    for (int n = 0; n < NOPE; n++) acc += qn[n] * w[(size_t)n * KVLORA];
    ushort* orow = qin + ((size_t)t * NH + h) * DQK;
    orow[tid] = f2bf(acc * scale);
    if (tid < 16) {
        float pos = (float)positions[t];
        float freq = powf(THETA, -(float)tid / 16.0f);
        float f = pos * freq;
        float c = cosf(f), s = sinf(f);
        float x1 = qrow[NOPE + tid], x2 = qrow[NOPE + 16 + tid];
        orow[KVLORA + tid]      = f2bf((x1 * c - x2 * s) * scale);
        orow[KVLORA + 16 + tid] = f2bf((x2 * c + x1 * s) * scale);
    }
}

// ---------------- flash MFMA attention ----------------
#define KSTR 296
#define VSTR 72
#define PSTR 72

__global__ __launch_bounds__(256, 2) void flash_attn(const ushort* __restrict__ qin,
                                                     const ushort* __restrict__ kin,
                                                     float* __restrict__ o_lat) {
    __shared__ ushort lds[64 * KSTR + 256 * VSTR];
    ushort* krow = lds;
    ushort* vt   = lds + 64 * KSTR;
    ushort* pbuf = lds;                 // alias of krow region

    const int tid  = threadIdx.x;
    const int lane = tid & 63;
    const int wv   = tid >> 6;
    const int col  = lane & 15;
    const int quad = lane >> 4;
    const int h    = blockIdx.y;
    const int qb   = ((int)gridDim.x - 1 - (int)blockIdx.x) * 64;

    bf16x8 qf[9];
    {
        const ushort* base = qin + ((size_t)(qb + wv * 16 + col) * NH + h) * DQK + quad * 8;
        #pragma unroll
        for (int k = 0; k < 9; k++) qf[k] = *(const bf16x8*)(base + k * 32);
    }

    f32x4 of[16];
    #pragma unroll
    for (int i = 0; i < 16; i++) of[i] = (f32x4){0.f, 0.f, 0.f, 0.f};
    float m_i[4] = {-1e30f, -1e30f, -1e30f, -1e30f};
    float l_i[4] = {0.f, 0.f, 0.f, 0.f};

    for (int s0 = 0; s0 <= qb; s0 += 64) {
        __syncthreads();
        {
            const ushort* src = kin + (size_t)(s0 + lane) * DQK;
            #pragma unroll
            for (int ci = 0; ci < 9; ci++) {
                int c = ci * 4 + wv;
                uint4 u = *(const uint4*)(src + c * 8);
                *(uint4*)(krow + lane * KSTR + c * 8) = u;
                if (c < 32) {
                    const ushort* up = (const ushort*)&u;
                    #pragma unroll
                    for (int j = 0; j < 8; j++)
                        vt[(c * 8 + j) * VSTR + lane] = up[j];
                }
            }
        }
        __syncthreads();
        f32x4 sf[4];
        #pragma unroll
        for (int tc = 0; tc < 4; tc++) sf[tc] = (f32x4){0.f, 0.f, 0.f, 0.f};
        #pragma unroll
        for (int k = 0; k < 9; k++) {
            #pragma unroll
            for (int tc = 0; tc < 4; tc++) {
                bf16x8 bf = *(const bf16x8*)(krow + (tc * 16 + col) * KSTR + k * 32 + quad * 8);
                sf[tc] = __builtin_amdgcn_mfma_f32_16x16x32_bf16(qf[k], bf, sf[tc], 0, 0, 0);
            }
        }
        if (s0 == qb) {
            #pragma unroll
            for (int tc = 0; tc < 4; tc++)
                #pragma unroll
                for (int r = 0; r < 4; r++)
                    if (tc * 16 + col > wv * 16 + quad * 4 + r) sf[tc][r] = -1e30f;
        }
        float mnew[4], alpha[4];
        #pragma unroll
        for (int r = 0; r < 4; r++) {
            float mx = fmaxf(fmaxf(sf[0][r], sf[1][r]), fmaxf(sf[2][r], sf[3][r]));
            mx = fmaxf(mx, __shfl_xor(mx, 1));
            mx = fmaxf(mx, __shfl_xor(mx, 2));
            mx = fmaxf(mx, __shfl_xor(mx, 4));
            mx = fmaxf(mx, __shfl_xor(mx, 8));
            mnew[r] = fmaxf(m_i[r], mx);
            alpha[r] = __expf(m_i[r] - mnew[r]);
            m_i[r] = mnew[r];
        }
        float rsum[4];
        #pragma unroll
        for (int r = 0; r < 4; r++) {
            float s = 0.f;
            #pragma unroll
            for (int tc = 0; tc < 4; tc++) {
                float p = __expf(sf[tc][r] - mnew[r]);
                sf[tc][r] = p;
                s += p;
            }
            s += __shfl_xor(s, 1);
            s += __shfl_xor(s, 2);
            s += __shfl_xor(s, 4);
            s += __shfl_xor(s, 8);
            rsum[r] = s;
        }
        #pragma unroll
        for (int r = 0; r < 4; r++) l_i[r] = l_i[r] * alpha[r] + rsum[r];
        #pragma unroll
        for (int i = 0; i < 16; i++)
            #pragma unroll
            for (int r = 0; r < 4; r++) of[i][r] *= alpha[r];
        __syncthreads();
        #pragma unroll
        for (int tc = 0; tc < 4; tc++)
            #pragma unroll
            for (int r = 0; r < 4; r++)
                pbuf[(wv * 16 + quad * 4 + r) * PSTR + tc * 16 + col] = f2bf(sf[tc][r]);
        __syncthreads();
        bf16x8 pa[2];
        #pragma unroll
        for (int ks = 0; ks < 2; ks++)
            pa[ks] = *(const bf16x8*)(pbuf + (wv * 16 + col) * PSTR + ks * 32 + quad * 8);
        #pragma unroll
        for (int nt = 0; nt < 16; nt++) {
            #pragma unroll
            for (int ks = 0; ks < 2; ks++) {
                bf16x8 vb = *(const bf16x8*)(vt + (nt * 16 + col) * VSTR + ks * 32 + quad * 8);
                of[nt] = __builtin_amdgcn_mfma_f32_16x16x32_bf16(pa[ks], vb, of[nt], 0, 0, 0);
            }
        }
    }
    #pragma unroll
    for (int r = 0; r < 4; r++) {
        float inv = 1.0f / l_i[r];
        int row = qb + wv * 16 + quad * 4 + r;
        float* dst = o_lat + ((size_t)row * NH + h) * KVLORA + col;
        #pragma unroll
        for (int nt = 0; nt < 16; nt++) dst[nt * 16] = of[nt][r] * inv;
    }
}

// ---------------- o_bf = o_lat @ w_vc[h]  (bf16 out for final GEMM) ----------------
__global__ __launch_bounds__(64) void ogemm(const float* __restrict__ o_lat,
                                            const float* __restrict__ w_vc,
                                            ushort* __restrict__ o) {
    int t = blockIdx.x, h = blockIdx.y, tid = threadIdx.x;
    __shared__ float ol[KVLORA];
    const float* row = o_lat + ((size_t)t * NH + h) * KVLORA;
    for (int i = tid; i < KVLORA; i += 64) ol[i] = row[i];
    __syncthreads();
    const float* w = w_vc + (size_t)h * KVLORA * VDIM + tid;
    float acc = 0.f;
    #pragma unroll 8
    for (int k = 0; k < KVLORA; k++) acc += ol[k] * w[(size_t)k * VDIM];
    o[(size_t)t * HID + h * VDIM + tid] = f2bf(acc);
}

extern "C" void kernel_launch(void* const* d_in, const int* in_sizes, int n_in,
                              void* d_out, int out_size, void* d_ws, size_t ws_size,
                              hipStream_t stream) {
    const int*   positions = (const int*)d_in[0];
    const float* hs    = (const float*)d_in[1];
    const float* w_qa  = (const float*)d_in[2];
    const float* g_qa  = (const float*)d_in[3];
    const float* w_qb  = (const float*)d_in[4];
    const float* w_kva = (const float*)d_in[5];
    const float* g_kva = (const float*)d_in[6];
    const float* w_kc  = (const float*)d_in[7];
    const float* w_vc  = (const float*)d_in[8];
    const float* w_o   = (const float*)d_in[9];
    float* out = (float*)d_out;

    float* ws    = (float*)d_ws;
    float* qa    = ws;                               // T*768
    float* q     = qa    + (size_t)TT * QLORA;       // T*3840
    float* kin   = q     + (size_t)TT * NH * QHD;    // T*288
    float* o_lat = kin   + (size_t)TT * DQK;         // T*40*256
    ushort* ub     = (ushort*)(o_lat + (size_t)TT * NH * KVLORA);
    ushort* hs_bf  = ub;                             // T*2560
    ushort* qa_bf  = hs_bf  + (size_t)TT * HID;      // T*768
    ushort* o_bf   = qa_bf  + (size_t)TT * QLORA;    // T*2560
    ushort* kin_bf = o_bf   + (size_t)TT * HID;      // T*288
    ushort* qin_bf = kin_bf + (size_t)TT * DQK;      // T*40*288
    ushort* w_qa_t  = qin_bf + (size_t)TT * NH * DQK;       // 768*2560
    ushort* w_qb_t  = w_qa_t + (size_t)QLORA * HID;         // 3840*768
    ushort* w_kva_t = w_qb_t + (size_t)(NH * QHD) * QLORA;  // 288*2560
    ushort* w_o_t   = w_kva_t + (size_t)DQK * HID;          // 2560*2560

    // ---- casts / transposes (independent of each other) ----
    cast_bf16<<<(TT * HID) / 1024, 256, 0, stream>>>(hs, hs_bf, TT * HID);
    transpose_cast<<<dim3(QLORA / 32, HID / 32), 256, 0, stream>>>(w_qa, w_qa_t, HID, QLORA);
    transpose_cast<<<dim3((NH * QHD) / 32, QLORA / 32), 256, 0, stream>>>(w_qb, w_qb_t, QLORA, NH * QHD);
    transpose_cast<<<dim3(DQK / 32, HID / 32), 256, 0, stream>>>(w_kva, w_kva_t, HID, DQK);
    transpose_cast<<<dim3(HID / 32, HID / 32), 256, 0, stream>>>(w_o, w_o_t, HID, HID);

    // 1. qa = hs @ w_qa (MFMA); RMS -> qa_bf
    gemm_bf16<<<dim3(QLORA / 128, TT / 128), 256, 0, stream>>>(hs_bf, w_qa_t, qa, TT, QLORA, HID);
    rms_qa<<<TT, 256, 0, stream>>>(qa, g_qa, qa_bf);
    // 2. q = qa @ w_qb (MFMA)
    gemm_bf16<<<dim3((NH * QHD) / 128, TT / 128), 256, 0, stream>>>(qa_bf, w_qb_t, q, TT, NH * QHD, QLORA);
    // 3. kin = hs @ w_kva (MFMA, N=288 edge); RMS+RoPE -> kin_bf
    gemm_bf16<<<dim3((DQK + 127) / 128, TT / 128), 256, 0, stream>>>(hs_bf, w_kva_t, kin, TT, DQK, HID);
    kin_post<<<TT, 256, 0, stream>>>(kin, g_kva, positions, kin_bf);
    // 4. qin_bf = [q_nope @ w_kc[h] | rope(q_pe)] * scale
    build_qin<<<dim3(TT, NH), 256, 0, stream>>>(q, w_kc, positions, qin_bf);
    // 5. flash MFMA attention
    flash_attn<<<dim3(TT / 64, NH), 256, 0, stream>>>(qin_bf, kin_bf, o_lat);
    // 6. o_bf = o_lat @ w_vc
    ogemm<<<dim3(TT, NH), 64, 0, stream>>>(o_lat, w_vc, o_bf);
    // 7. out = o_bf @ w_o (MFMA)
    gemm_bf16<<<dim3(HID / 128, TT / 128), 256, 0, stream>>>(o_bf, w_o_t, out, TT, HID, HID);
}